// Round 1
// baseline (577.066 us; speedup 1.0000x reference)
//
#include <hip/hip_runtime.h>

// Problem constants
#define BATCH 32
#define TT    2048
#define HH    1024
#define MTOT  (BATCH * TT)   // 65536

typedef unsigned short ushort_t;
typedef short sh8 __attribute__((ext_vector_type(8)));
typedef float f4 __attribute__((ext_vector_type(4)));
typedef unsigned short us8 __attribute__((ext_vector_type(8)));

__device__ __forceinline__ ushort_t f2bf(float f) {
    unsigned u = __float_as_uint(f);
    u = (u + 0x7fffu + ((u >> 16) & 1u)) >> 16;
    return (ushort_t)u;
}
__device__ __forceinline__ float bf2f(ushort_t h) {
    return __uint_as_float(((unsigned)h) << 16);
}
__device__ __forceinline__ float fast_tanh(float x) {
    float e = __expf(2.0f * x);                  // v_exp_f32 path
    return 1.0f - 2.0f * __builtin_amdgcn_rcpf(e + 1.0f);
}

__device__ __forceinline__ void glds16(const void* g, void* l) {
    __builtin_amdgcn_global_load_lds(
        (const __attribute__((address_space(1))) void*)g,
        (__attribute__((address_space(3))) void*)l, 16, 0, 0);
}

// ---------------- fp32 -> bf16 convert (8 elems/thread) ----------------
__global__ void cvt_bf16_k(const float* __restrict__ in, ushort_t* __restrict__ out, long n) {
    long i = ((long)blockIdx.x * blockDim.x + threadIdx.x) * 8;
    if (i + 8 > n) return;
    float4 a = *(const float4*)(in + i);
    float4 b = *(const float4*)(in + i + 4);
    us8 o;
    o[0]=f2bf(a.x); o[1]=f2bf(a.y); o[2]=f2bf(a.z); o[3]=f2bf(a.w);
    o[4]=f2bf(b.x); o[5]=f2bf(b.y); o[6]=f2bf(b.z); o[7]=f2bf(b.w);
    *(us8*)(out + i) = o;
}

// ---------------- q_proj = query @ Wq.T + bq + bv ----------------
// grid = 1024 (one block per output column o), block = 256
__global__ void qproj_k(const float* __restrict__ query, const float* __restrict__ Wq,
                        const float* __restrict__ bq, const float* __restrict__ bv,
                        float* __restrict__ qp) {
    int o = blockIdx.x, tid = threadIdx.x;
    float4 w4 = *(const float4*)(Wq + (long)o * HH + tid * 4);
    __shared__ float sm[BATCH][4];
    int wid = tid >> 6, lane = tid & 63;
    for (int b = 0; b < BATCH; ++b) {
        float4 q4 = *(const float4*)(query + (long)b * HH + tid * 4);
        float p = q4.x*w4.x + q4.y*w4.y + q4.z*w4.z + q4.w*w4.w;
        #pragma unroll
        for (int m = 1; m < 64; m <<= 1) p += __shfl_xor(p, m);
        if (lane == 0) sm[b][wid] = p;
    }
    __syncthreads();
    if (tid < BATCH) {
        float s = sm[tid][0] + sm[tid][1] + sm[tid][2] + sm[tid][3] + bq[o] + bv[o];
        qp[(long)tid * HH + o] = s;
    }
}

// ---------------- fused score GEMM ----------------
// score[m] += sum_{n in tile} tanh(C[m,n] + qp[b,n]) * Vw[n]
// A = values bf16 [65536][1024], B = Wv bf16 [1024][1024] (both K-contiguous, NT gemm)
#define BM 128
#define BN 128
#define BK 64

__global__ __launch_bounds__(256, 2) void score_gemm_k(
    const ushort_t* __restrict__ A, const ushort_t* __restrict__ Bw,
    const float* __restrict__ qp, const float* __restrict__ Vw,
    float* __restrict__ score)
{
    __shared__ ushort_t As[BM * BK];   // 16 KB
    __shared__ ushort_t Bs[BN * BK];   // 16 KB
    int tid = threadIdx.x;

    // XCD-aware swizzle: all 8 n-tiles of one m-tile land on the same XCD (blockIdx%8 assumption)
    int bx = blockIdx.x;
    int x  = bx & 7;
    int s  = bx >> 3;
    int nt = s & 7;
    int mt = ((s >> 3) << 3) | x;          // 0..511
    const long m0 = (long)mt * BM;
    const int  n0 = nt * BN;

    int wid  = tid >> 6, lane = tid & 63;
    int quad = lane >> 4, l16 = lane & 15;
    int wrow = (wid >> 1) * 64, wcol = (wid & 1) * 64;

    f4 acc[4][4] = {};

    // staging: thread -> (row = tid/8, 16B seg = tid%8), seg XOR-swizzled by row&7
    int srow = tid >> 3;
    int sseg = tid & 7;
    int xseg = sseg ^ (srow & 7);
    const ushort_t* Ag = A  + (m0 + srow) * (long)HH + xseg * 8;
    const ushort_t* Bg = Bw + (long)(n0 + srow) * HH + xseg * 8;
    char* AsB = (char*)As;
    char* BsB = (char*)Bs;
    const int ldsOff = wid * 1024;   // wave-uniform; HW adds lane*16

    for (int kt = 0; kt < HH / BK; ++kt) {
        const int kb = kt * BK;
        #pragma unroll
        for (int c = 0; c < 4; ++c) {
            glds16(Ag + (long)c * 32 * HH + kb, AsB + c * 4096 + ldsOff);
            glds16(Bg + (long)c * 32 * HH + kb, BsB + c * 4096 + ldsOff);
        }
        __syncthreads();

        sh8 af[4][2], bf[4][2];
        #pragma unroll
        for (int i = 0; i < 4; ++i) {
            int r = wrow + i * 16 + l16;
            #pragma unroll
            for (int kq = 0; kq < 2; ++kq) {
                int sg = (kq * 4 + quad) ^ (r & 7);
                af[i][kq] = *(const sh8*)(AsB + r * 128 + sg * 16);
            }
        }
        #pragma unroll
        for (int j = 0; j < 4; ++j) {
            int r = wcol + j * 16 + l16;
            #pragma unroll
            for (int kq = 0; kq < 2; ++kq) {
                int sg = (kq * 4 + quad) ^ (r & 7);
                bf[j][kq] = *(const sh8*)(BsB + r * 128 + sg * 16);
            }
        }
        #pragma unroll
        for (int kq = 0; kq < 2; ++kq)
            #pragma unroll
            for (int i = 0; i < 4; ++i)
                #pragma unroll
                for (int j = 0; j < 4; ++j)
                    acc[i][j] = __builtin_amdgcn_mfma_f32_16x16x32_bf16(
                        af[i][kq], bf[j][kq], acc[i][j], 0, 0, 0);
        __syncthreads();
    }

    // ---- epilogue: per-row tanh-dot with Vw, reduce over the 16 col-lanes, atomicAdd ----
    int bidx = (int)(m0 >> 11);                 // m0 / 2048
    const float* qpb = qp + (long)bidx * HH;
    float qv[4], vw[4];
    #pragma unroll
    for (int j = 0; j < 4; ++j) {
        int cg = n0 + wcol + j * 16 + l16;      // C/D col = lane&15
        qv[j] = qpb[cg];
        vw[j] = Vw[cg];
    }
    #pragma unroll
    for (int i = 0; i < 4; ++i) {
        #pragma unroll
        for (int r = 0; r < 4; ++r) {
            float sum = 0.0f;
            #pragma unroll
            for (int j = 0; j < 4; ++j) {
                float xv = acc[i][j][r] + qv[j];
                sum += fast_tanh(xv) * vw[j];
            }
            sum += __shfl_xor(sum, 1);
            sum += __shfl_xor(sum, 2);
            sum += __shfl_xor(sum, 4);
            sum += __shfl_xor(sum, 8);
            if (l16 == 0) {
                // C/D row = quad*4 + reg
                atomicAdd(score + m0 + wrow + i * 16 + quad * 4 + r, sum);
            }
        }
    }
}

// ---------------- softmax over T per batch ----------------
__global__ void softmax_k(const float* __restrict__ sc, float* __restrict__ w) {
    int b = blockIdx.x, tid = threadIdx.x;
    const float* s = sc + (long)b * TT;
    float v[8];
    float4 a0 = *(const float4*)(s + tid * 8);
    float4 a1 = *(const float4*)(s + tid * 8 + 4);
    v[0]=a0.x; v[1]=a0.y; v[2]=a0.z; v[3]=a0.w;
    v[4]=a1.x; v[5]=a1.y; v[6]=a1.z; v[7]=a1.w;
    float mx = v[0];
    #pragma unroll
    for (int i = 1; i < 8; ++i) mx = fmaxf(mx, v[i]);
    #pragma unroll
    for (int m = 1; m < 64; m <<= 1) mx = fmaxf(mx, __shfl_xor(mx, m));
    __shared__ float smx[4], ssum[4];
    int wid = tid >> 6;
    if ((tid & 63) == 0) smx[wid] = mx;
    __syncthreads();
    mx = fmaxf(fmaxf(smx[0], smx[1]), fmaxf(smx[2], smx[3]));
    float sum = 0.0f;
    #pragma unroll
    for (int i = 0; i < 8; ++i) { v[i] = __expf(v[i] - mx); sum += v[i]; }
    #pragma unroll
    for (int m = 1; m < 64; m <<= 1) sum += __shfl_xor(sum, m);
    if ((tid & 63) == 0) ssum[wid] = sum;
    __syncthreads();
    sum = ssum[0] + ssum[1] + ssum[2] + ssum[3];
    float inv = 1.0f / sum;
    float4 o0 = make_float4(v[0]*inv, v[1]*inv, v[2]*inv, v[3]*inv);
    float4 o1 = make_float4(v[4]*inv, v[5]*inv, v[6]*inv, v[7]*inv);
    *(float4*)(w + (long)b * TT + tid * 8)     = o0;
    *(float4*)(w + (long)b * TT + tid * 8 + 4) = o1;
}

// ---------------- context = sum_t w[b,t] * values[b,t,:] ----------------
// grid = (32, 16): b x t-chunk of 128; block = 256, 4 h per thread
__global__ void context_k(const ushort_t* __restrict__ vb, const float* __restrict__ w,
                          float* __restrict__ out) {
    int b = blockIdx.x, tc = blockIdx.y;
    int h = threadIdx.x * 4;
    const ushort_t* base = vb + (long)b * TT * HH;
    float4 acc = make_float4(0.f, 0.f, 0.f, 0.f);
    int t0 = tc * 128;
    for (int t = t0; t < t0 + 128; ++t) {
        float wt = w[(long)b * TT + t];
        ushort4 v = *(const ushort4*)(base + (long)t * HH + h);
        acc.x += wt * bf2f(v.x);
        acc.y += wt * bf2f(v.y);
        acc.z += wt * bf2f(v.z);
        acc.w += wt * bf2f(v.w);
    }
    float* o = out + (long)b * HH + h;
    atomicAdd(o + 0, acc.x);
    atomicAdd(o + 1, acc.y);
    atomicAdd(o + 2, acc.z);
    atomicAdd(o + 3, acc.w);
}

extern "C" void kernel_launch(void* const* d_in, const int* in_sizes, int n_in,
                              void* d_out, int out_size, void* d_ws, size_t ws_size,
                              hipStream_t stream) {
    const float* query  = (const float*)d_in[0];
    const float* values = (const float*)d_in[1];
    const float* Wq     = (const float*)d_in[2];
    const float* bq     = (const float*)d_in[3];
    const float* Wv     = (const float*)d_in[4];
    const float* bv     = (const float*)d_in[5];
    const float* Vw     = (const float*)d_in[6];
    // Vb (d_in[7]) cancels in softmax; score itself is not an output.

    // workspace layout
    char* ws = (char*)d_ws;
    ushort_t* vb   = (ushort_t*)ws;                                    // 64Mi bf16 = 128 MB
    ushort_t* wvb  = (ushort_t*)(ws + 134217728);                      // 1Mi bf16 = 2 MB
    float*    qp   = (float*)   (ws + 134217728 + 2097152);            // 32x1024 fp32
    float*    scre = (float*)   (ws + 134217728 + 2097152 + 131072);   // 65536 fp32

    float* ctx  = (float*)d_out;               // [32,1024]
    float* wout = (float*)d_out + BATCH * HH;  // [32,2048,1]

    hipMemsetAsync(scre, 0, (size_t)MTOT * 4, stream);
    hipMemsetAsync(ctx,  0, (size_t)BATCH * HH * 4, stream);

    // convert values + Wv to bf16
    cvt_bf16_k<<<(BATCH * TT * HH) / 2048, 256, 0, stream>>>(values, vb, (long)BATCH * TT * HH);
    cvt_bf16_k<<<(HH * HH) / 2048, 256, 0, stream>>>(Wv, wvb, (long)HH * HH);

    // q_proj (+bq +bv folded)
    qproj_k<<<HH, 256, 0, stream>>>(query, Wq, bq, bv, qp);

    // fused score GEMM: 512 m-tiles x 8 n-tiles
    score_gemm_k<<<(MTOT / BM) * (HH / BN), 256, 0, stream>>>(vb, wvb, qp, Vw, scre);

    // softmax over T
    softmax_k<<<BATCH, 256, 0, stream>>>(scre, wout);

    // context vector
    context_k<<<dim3(BATCH, 16), 256, 0, stream>>>(vb, wout, ctx);
}

// Round 2
// 565.339 us; speedup vs baseline: 1.0207x; 1.0207x over previous
//
#include <hip/hip_runtime.h>

// Problem constants
#define BATCH 32
#define TT    2048
#define HH    1024
#define MTOT  (BATCH * TT)   // 65536

typedef unsigned short ushort_t;
typedef short sh8 __attribute__((ext_vector_type(8)));
typedef float f4 __attribute__((ext_vector_type(4)));
typedef unsigned short us8 __attribute__((ext_vector_type(8)));

__device__ __forceinline__ ushort_t f2bf(float f) {
    unsigned u = __float_as_uint(f);
    u = (u + 0x7fffu + ((u >> 16) & 1u)) >> 16;
    return (ushort_t)u;
}
__device__ __forceinline__ float bf2f(ushort_t h) {
    return __uint_as_float(((unsigned)h) << 16);
}
__device__ __forceinline__ float fast_tanh(float x) {
    float e = __expf(2.0f * x);                  // v_exp_f32 path
    return 1.0f - 2.0f * __builtin_amdgcn_rcpf(e + 1.0f);
}

__device__ __forceinline__ void glds16(const void* g, void* l) {
    __builtin_amdgcn_global_load_lds(
        (const __attribute__((address_space(1))) void*)g,
        (__attribute__((address_space(3))) void*)l, 16, 0, 0);
}

// ---------------- fp32 -> bf16 convert (8 elems/thread) ----------------
__global__ void cvt_bf16_k(const float* __restrict__ in, ushort_t* __restrict__ out, long n) {
    long i = ((long)blockIdx.x * blockDim.x + threadIdx.x) * 8;
    if (i + 8 > n) return;
    float4 a = *(const float4*)(in + i);
    float4 b = *(const float4*)(in + i + 4);
    us8 o;
    o[0]=f2bf(a.x); o[1]=f2bf(a.y); o[2]=f2bf(a.z); o[3]=f2bf(a.w);
    o[4]=f2bf(b.x); o[5]=f2bf(b.y); o[6]=f2bf(b.z); o[7]=f2bf(b.w);
    *(us8*)(out + i) = o;
}

// ---------------- q_proj = query @ Wq.T + bq + bv ----------------
// grid = 1024 (one block per output column o), block = 256
__global__ void qproj_k(const float* __restrict__ query, const float* __restrict__ Wq,
                        const float* __restrict__ bq, const float* __restrict__ bv,
                        float* __restrict__ qp) {
    int o = blockIdx.x, tid = threadIdx.x;
    float4 w4 = *(const float4*)(Wq + (long)o * HH + tid * 4);
    __shared__ float sm[BATCH][4];
    int wid = tid >> 6, lane = tid & 63;
    for (int b = 0; b < BATCH; ++b) {
        float4 q4 = *(const float4*)(query + (long)b * HH + tid * 4);
        float p = q4.x*w4.x + q4.y*w4.y + q4.z*w4.z + q4.w*w4.w;
        #pragma unroll
        for (int m = 1; m < 64; m <<= 1) p += __shfl_xor(p, m);
        if (lane == 0) sm[b][wid] = p;
    }
    __syncthreads();
    if (tid < BATCH) {
        float s = sm[tid][0] + sm[tid][1] + sm[tid][2] + sm[tid][3] + bq[o] + bv[o];
        qp[(long)tid * HH + o] = s;
    }
}

// ---------------- fused score GEMM ----------------
// score[m] += sum_{n in tile} tanh(C[m,n] + qp[b,n]) * Vw[n]
// A = values bf16 [65536][1024], B = Wv bf16 [1024][1024] (both K-contiguous, NT gemm)
#define BM 128
#define BN 128
#define BK 64

__global__ __launch_bounds__(256, 2) void score_gemm_k(
    const ushort_t* __restrict__ A, const ushort_t* __restrict__ Bw,
    const float* __restrict__ qp, const float* __restrict__ Vw,
    float* __restrict__ score)
{
    __shared__ ushort_t As[BM * BK];   // 16 KB
    __shared__ ushort_t Bs[BN * BK];   // 16 KB
    int tid = threadIdx.x;

    // XCD-aware swizzle: all 8 n-tiles of one m-tile land on the same XCD (blockIdx%8 assumption)
    int bx = blockIdx.x;
    int x  = bx & 7;
    int s  = bx >> 3;
    int nt = s & 7;
    int mt = ((s >> 3) << 3) | x;          // 0..511
    const long m0 = (long)mt * BM;
    const int  n0 = nt * BN;

    int wid  = tid >> 6, lane = tid & 63;
    int quad = lane >> 4, l16 = lane & 15;
    int wrow = (wid >> 1) * 64, wcol = (wid & 1) * 64;

    f4 acc[4][4] = {};

    // staging: thread -> (row = tid/8, 16B seg = tid%8), seg XOR-swizzled by row&7
    int srow = tid >> 3;
    int sseg = tid & 7;
    int xseg = sseg ^ (srow & 7);
    const ushort_t* Ag = A  + (m0 + srow) * (long)HH + xseg * 8;
    const ushort_t* Bg = Bw + (long)(n0 + srow) * HH + xseg * 8;
    char* AsB = (char*)As;
    char* BsB = (char*)Bs;
    const int ldsOff = wid * 1024;   // wave-uniform; HW adds lane*16

    for (int kt = 0; kt < HH / BK; ++kt) {
        const int kb = kt * BK;
        #pragma unroll
        for (int c = 0; c < 4; ++c) {
            glds16(Ag + (long)c * 32 * HH + kb, AsB + c * 4096 + ldsOff);
            glds16(Bg + (long)c * 32 * HH + kb, BsB + c * 4096 + ldsOff);
        }
        __syncthreads();

        sh8 af[4][2], bf[4][2];
        #pragma unroll
        for (int i = 0; i < 4; ++i) {
            int r = wrow + i * 16 + l16;
            #pragma unroll
            for (int kq = 0; kq < 2; ++kq) {
                int sg = (kq * 4 + quad) ^ (r & 7);
                af[i][kq] = *(const sh8*)(AsB + r * 128 + sg * 16);
            }
        }
        #pragma unroll
        for (int j = 0; j < 4; ++j) {
            int r = wcol + j * 16 + l16;
            #pragma unroll
            for (int kq = 0; kq < 2; ++kq) {
                int sg = (kq * 4 + quad) ^ (r & 7);
                bf[j][kq] = *(const sh8*)(BsB + r * 128 + sg * 16);
            }
        }
        #pragma unroll
        for (int kq = 0; kq < 2; ++kq)
            #pragma unroll
            for (int i = 0; i < 4; ++i)
                #pragma unroll
                for (int j = 0; j < 4; ++j)
                    acc[i][j] = __builtin_amdgcn_mfma_f32_16x16x32_bf16(
                        af[i][kq], bf[j][kq], acc[i][j], 0, 0, 0);
        __syncthreads();
    }

    // ---- epilogue: per-row tanh-dot with Vw, reduce over the 16 col-lanes, atomicAdd ----
    int bidx = (int)(m0 >> 11);                 // m0 / 2048
    const float* qpb = qp + (long)bidx * HH;
    float qv[4], vw[4];
    #pragma unroll
    for (int j = 0; j < 4; ++j) {
        int cg = n0 + wcol + j * 16 + l16;      // C/D col = lane&15
        qv[j] = qpb[cg];
        vw[j] = Vw[cg];
    }
    #pragma unroll
    for (int i = 0; i < 4; ++i) {
        #pragma unroll
        for (int r = 0; r < 4; ++r) {
            float sum = 0.0f;
            #pragma unroll
            for (int j = 0; j < 4; ++j) {
                float xv = acc[i][j][r] + qv[j];
                sum += fast_tanh(xv) * vw[j];
            }
            sum += __shfl_xor(sum, 1);
            sum += __shfl_xor(sum, 2);
            sum += __shfl_xor(sum, 4);
            sum += __shfl_xor(sum, 8);
            if (l16 == 0) {
                // C/D row = quad*4 + reg
                atomicAdd(score + m0 + wrow + i * 16 + quad * 4 + r, sum);
            }
        }
    }
}

// ---------------- softmax over T per batch ----------------
__global__ void softmax_k(const float* __restrict__ sc, float* __restrict__ w) {
    int b = blockIdx.x, tid = threadIdx.x;
    const float* s = sc + (long)b * TT;
    float v[8];
    float4 a0 = *(const float4*)(s + tid * 8);
    float4 a1 = *(const float4*)(s + tid * 8 + 4);
    v[0]=a0.x; v[1]=a0.y; v[2]=a0.z; v[3]=a0.w;
    v[4]=a1.x; v[5]=a1.y; v[6]=a1.z; v[7]=a1.w;
    float mx = v[0];
    #pragma unroll
    for (int i = 1; i < 8; ++i) mx = fmaxf(mx, v[i]);
    #pragma unroll
    for (int m = 1; m < 64; m <<= 1) mx = fmaxf(mx, __shfl_xor(mx, m));
    __shared__ float smx[4], ssum[4];
    int wid = tid >> 6;
    if ((tid & 63) == 0) smx[wid] = mx;
    __syncthreads();
    mx = fmaxf(fmaxf(smx[0], smx[1]), fmaxf(smx[2], smx[3]));
    float sum = 0.0f;
    #pragma unroll
    for (int i = 0; i < 8; ++i) { v[i] = __expf(v[i] - mx); sum += v[i]; }
    #pragma unroll
    for (int m = 1; m < 64; m <<= 1) sum += __shfl_xor(sum, m);
    if ((tid & 63) == 0) ssum[wid] = sum;
    __syncthreads();
    sum = ssum[0] + ssum[1] + ssum[2] + ssum[3];
    float inv = 1.0f / sum;
    float4 o0 = make_float4(v[0]*inv, v[1]*inv, v[2]*inv, v[3]*inv);
    float4 o1 = make_float4(v[4]*inv, v[5]*inv, v[6]*inv, v[7]*inv);
    *(float4*)(w + (long)b * TT + tid * 8)     = o0;
    *(float4*)(w + (long)b * TT + tid * 8 + 4) = o1;
}

// ---------------- context partial: grid (32,16), block 256 ----------------
// block (b, tc): t-chunk of 128. thread: toff = tid>>7 (t parity), h8 = (tid&127)*8.
// 16 B/lane loads, 8 in flight, weights staged in LDS, no atomics.
__global__ void context_k2(const ushort_t* __restrict__ vb, const float* __restrict__ w,
                           float* __restrict__ partial) {
    int b = blockIdx.x, tc = blockIdx.y;
    int tid = threadIdx.x;
    int toff = tid >> 7;            // 0 or 1
    int hi   = tid & 127;
    int h    = hi * 8;
    __shared__ float sw[128];
    __shared__ float red[128][8];   // 4 KB
    if (tid < 128) sw[tid] = w[(long)b * TT + tc * 128 + tid];
    __syncthreads();

    const ushort_t* base = vb + ((long)b * TT + tc * 128 + toff) * HH + h;
    float acc[8] = {0.f,0.f,0.f,0.f,0.f,0.f,0.f,0.f};
    #pragma unroll 8
    for (int it = 0; it < 64; ++it) {
        us8 v = *(const us8*)(base + (long)it * 2 * HH);
        float wt = sw[it * 2 + toff];
        #pragma unroll
        for (int e = 0; e < 8; ++e) acc[e] += wt * bf2f(v[e]);
    }
    if (toff == 1) {
        #pragma unroll
        for (int e = 0; e < 8; ++e) red[hi][e] = acc[e];
    }
    __syncthreads();
    if (toff == 0) {
        #pragma unroll
        for (int e = 0; e < 8; ++e) acc[e] += red[hi][e];
        float* p = partial + ((long)tc * 32 + b) * HH + h;
        *(float4*)(p)     = make_float4(acc[0], acc[1], acc[2], acc[3]);
        *(float4*)(p + 4) = make_float4(acc[4], acc[5], acc[6], acc[7]);
    }
}

// ---------------- context reduce: 128 blocks x 256 ----------------
__global__ void context_red_k(const float* __restrict__ partial, float* __restrict__ ctx) {
    int i = blockIdx.x * 256 + threadIdx.x;   // over 32*1024
    float s = 0.f;
    #pragma unroll
    for (int tc = 0; tc < 16; ++tc) s += partial[(long)tc * 32768 + i];
    ctx[i] = s;
}

extern "C" void kernel_launch(void* const* d_in, const int* in_sizes, int n_in,
                              void* d_out, int out_size, void* d_ws, size_t ws_size,
                              hipStream_t stream) {
    const float* query  = (const float*)d_in[0];
    const float* values = (const float*)d_in[1];
    const float* Wq     = (const float*)d_in[2];
    const float* bq     = (const float*)d_in[3];
    const float* Wv     = (const float*)d_in[4];
    const float* bv     = (const float*)d_in[5];
    const float* Vw     = (const float*)d_in[6];
    // Vb (d_in[7]) cancels in softmax; score itself is not an output.

    // workspace layout (same footprint as R1 — partial reuses the dead wvb region)
    char* ws = (char*)d_ws;
    ushort_t* vb   = (ushort_t*)ws;                                    // 64Mi bf16 = 128 MB
    ushort_t* wvb  = (ushort_t*)(ws + 134217728);                      // 1Mi bf16 = 2 MB
    float*    qp   = (float*)   (ws + 134217728 + 2097152);            // 32x1024 fp32
    float*    scre = (float*)   (ws + 134217728 + 2097152 + 131072);   // 65536 fp32
    float*    partial = (float*)wvb;  // 16x32x1024 fp32 = 2 MB; wvb dead after gemm

    float* ctx  = (float*)d_out;               // [32,1024]
    float* wout = (float*)d_out + BATCH * HH;  // [32,2048,1]

    hipMemsetAsync(scre, 0, (size_t)MTOT * 4, stream);

    // convert values + Wv to bf16
    cvt_bf16_k<<<(BATCH * TT * HH) / 2048, 256, 0, stream>>>(values, vb, (long)BATCH * TT * HH);
    cvt_bf16_k<<<(HH * HH) / 2048, 256, 0, stream>>>(Wv, wvb, (long)HH * HH);

    // q_proj (+bq +bv folded)
    qproj_k<<<HH, 256, 0, stream>>>(query, Wq, bq, bv, qp);

    // fused score GEMM: 512 m-tiles x 8 n-tiles
    score_gemm_k<<<(MTOT / BM) * (HH / BN), 256, 0, stream>>>(vb, wvb, qp, Vw, scre);

    // softmax over T
    softmax_k<<<BATCH, 256, 0, stream>>>(scre, wout);

    // context vector: partials (no atomics) + reduce
    context_k2<<<dim3(BATCH, 16), 256, 0, stream>>>(vb, wout, partial);
    context_red_k<<<(BATCH * HH) / 256, 256, 0, stream>>>(partial, ctx);
}